// Round 6
// baseline (146.815 us; speedup 1.0000x reference)
//
#include <hip/hip_runtime.h>
#include <hip/hip_bf16.h>
#include <cstdint>
#include <cstddef>

// ---------------------------------------------------------------------------
// R6: fc3 -> double-buffered 2-phase pipeline (counted vmcnt(6), raw
//     s_barrier); conv1 -> row-strip lanes (b128 xq reads, stride-20 pad);
//     cvt kernels merged. Structure otherwise as R5.
// ---------------------------------------------------------------------------

typedef __bf16 bf16x8v __attribute__((ext_vector_type(8)));
typedef float  f32x4   __attribute__((ext_vector_type(4)));

#define WAVE_FENCE() asm volatile("s_waitcnt lgkmcnt(0)" ::: "memory")

#define A1_PS 24
#define A1_RS (13 * A1_PS)          // 312
#define A1_ZS (12 * A1_RS)          // zero slot
#define A1_BS 3776                  // per-batch elems (7552 B)
#define XQ_RS 20                    // padded row stride (floats), 16B-aligned
#define XQ_BS 256                   // 12*20 + pad

#define FC3_K 3584                  // permuted/padded K (7 Mtiles * 512)

// ---------------- all weight converts in one launch ----------------
// blocks [0,3584): w3p ; [3584,3604): w2p ; [3604,3860): wfi ; [3860,3924): wfh
__global__ __launch_bounds__(256) void cvt_all_k(
    const float* __restrict__ fc3w, const float* __restrict__ w2g,
    const float* __restrict__ wih,  const float* __restrict__ whh,
    __hip_bfloat16* __restrict__ w3p, __hip_bfloat16* __restrict__ w2p,
    __hip_bfloat16* __restrict__ wfi, __hip_bfloat16* __restrict__ wfh)
{
    int bid = blockIdx.x;
    if (bid < 3584) {
        int idx = bid * 256 + threadIdx.x;
        int n = idx / FC3_K, kp = idx % FC3_K;
        int mt = kp >> 9, r = kp & 511;
        int fq = r >> 7, col = (r >> 3) & 15, nt = (r >> 2) & 1, j = r & 3;
        int pixel = mt * 16 + fq * 4 + j, oc = nt * 16 + col;
        float v = (pixel < 110) ? fc3w[n * 3520 + oc * 110 + pixel] : 0.f;
        w3p[idx] = __float2bfloat16(v);
    } else if (bid < 3604) {
        int idx = (bid - 3584) * 256 + threadIdx.x;
        if (idx < 5120) {
            int oc = idx / 160, k = idx % 160;
            int koff = k >> 4, ic = k & 15;
            float v = (koff < 9) ? w2g[(oc * 16 + ic) * 9 + koff] : 0.f;
            w2p[idx] = __float2bfloat16(v);
        }
    } else if (bid < 3860) {
        int idx = (bid - 3604) * 256 + threadIdx.x;   // < 65536
        int e = idx & 7, lane = (idx >> 3) & 63, hl = (idx >> 9) & 1;
        int kt = (idx >> 10) & 7, nt = (idx >> 13) & 7;
        int gate = nt * 16 + (lane & 15);
        int k = kt * 32 + (lane >> 4) * 8 + e;
        float v = wih[gate * 256 + k];
        __hip_bfloat16 hi = __float2bfloat16(v);
        wfi[idx] = hl ? __float2bfloat16(v - __bfloat162float(hi)) : hi;
    } else {
        int idx = (bid - 3860) * 256 + threadIdx.x;   // < 16384
        int e = idx & 7, lane = (idx >> 3) & 63, hl = (idx >> 9) & 1;
        int kt = (idx >> 10) & 1, nt = (idx >> 11) & 7;
        int gate = nt * 16 + (lane & 15);
        int k = kt * 32 + (lane >> 4) * 8 + e;
        float v = whh[gate * 64 + k];
        __hip_bfloat16 hi = __float2bfloat16(v);
        wfh[idx] = hl ? __float2bfloat16(v - __bfloat162float(hi)) : hi;
    }
}

// ---------------- all-steps fused quant + conv1 + conv2 ----------------
// grid 5120 = 10 t * 512; block = 4 waves, wave = 1 (batch, t), no barriers.
// conv1 lanes: ocp = lane&7 (oc pair), rs = lane>>3 (image row; rows 8,9 by
// rs 0,1 in pass 2). Row-window reads as b128.
__global__ __launch_bounds__(256) void conv_all_k(
    const float* __restrict__ x, const float* __restrict__ w1g,
    const __hip_bfloat16* __restrict__ w2p,
    __hip_bfloat16* __restrict__ a2p)
{
    __shared__ __hip_bfloat16 a1_s[4 * A1_BS];
    __shared__ float xq_s[4 * XQ_BS];

    const int tid  = threadIdx.x;
    const int wv   = tid >> 6, lane = tid & 63;
    const int t    = blockIdx.x >> 9;
    const int b    = (blockIdx.x & 511) * 4 + wv;
    const int ab   = wv * A1_BS;
    const int xb   = wv * XQ_BS;

    const int fr  = lane & 15, fq = lane >> 4;
    const int fqh = fq >> 1,  icb = (fq & 1) * 8;

    bf16x8v bfrag[5][2];
#pragma unroll
    for (int kt = 0; kt < 5; ++kt)
#pragma unroll
        for (int nt = 0; nt < 2; ++nt)
            bfrag[kt][nt] = *(const bf16x8v*)&w2p[(nt * 16 + fr) * 160 + kt * 32 + fq * 8];

    const int ocp = lane & 7, rs = lane >> 3;
    float w1a[9], w1b[9];
#pragma unroll
    for (int k = 0; k < 9; ++k) {
        w1a[k] = w1g[(2 * ocp) * 9 + k];
        w1b[k] = w1g[(2 * ocp + 1) * 9 + k];
    }

    {
        bf16x8v z = {};
#pragma unroll
        for (int i = 0; i < 8; ++i) {
            int c = lane + i * 64;
            if (c < A1_BS / 8) *(bf16x8v*)&a1_s[ab + c * 8] = z;
        }
        float4 zf = {0.f, 0.f, 0.f, 0.f};
        *(float4*)&xq_s[xb + lane * 4] = zf;      // 64*4 = 256 = XQ_BS
    }
    WAVE_FENCE();

#pragma unroll
    for (int pass = 0; pass < 2; ++pass) {
        int p = pass * 64 + lane;
        if (p < 110) {
            float xv = x[(size_t)b * 1100 + t * 110 + p];
            xv = fminf(fmaxf(xv, -1.f), 1.f);
            xv = rintf(xv * 128.f) * 0.0078125f;
            int h = p / 11, w = p - h * 11;
            xq_s[xb + (h + 1) * XQ_RS + (w + 1)] = xv;
        }
    }
    WAVE_FENCE();

    // conv1: lane does oc pair (2*ocp,2*ocp+1) for image row(s) rs (+8)
#pragma unroll
    for (int pass = 0; pass < 2; ++pass) {
        const int hr = pass == 0 ? rs : rs + 8;
        if (hr < 10) {
            float acc0[11], acc1[11];
#pragma unroll
            for (int w = 0; w < 11; ++w) { acc0[w] = 0.f; acc1[w] = 0.f; }
#pragma unroll
            for (int dr = 0; dr < 3; ++dr) {
                float xr[16];
                const float* row = &xq_s[xb + (hr + dr) * XQ_RS];
#pragma unroll
                for (int j = 0; j < 4; ++j)
                    *(float4*)&xr[j * 4] = *(const float4*)&row[j * 4];
#pragma unroll
                for (int dc = 0; dc < 3; ++dc) {
                    float wa = w1a[dr * 3 + dc], wb = w1b[dr * 3 + dc];
#pragma unroll
                    for (int w = 0; w < 11; ++w) {
                        acc0[w] += xr[w + dc] * wa;
                        acc1[w] += xr[w + dc] * wb;
                    }
                }
            }
#pragma unroll
            for (int w = 0; w < 11; ++w) {
                __hip_bfloat162 pr;
                pr.x = __float2bfloat16(fminf(fmaxf(acc0[w], 0.f), 1.f));
                pr.y = __float2bfloat16(fminf(fmaxf(acc1[w], 0.f), 1.f));
                *(__hip_bfloat162*)&a1_s[ab + (hr + 1) * A1_RS + (w + 1) * A1_PS + 2 * ocp] = pr;
            }
        }
    }
    WAVE_FENCE();

    const int d0 = fqh * 24 + icb;
    const int d1 = (fqh ? 312 : 48) + icb;
    const int d2 = 336 + fqh * 24 + icb;
    const int d3 = 624 + fqh * 24 + icb;

#pragma unroll
    for (int m = 0; m < 7; ++m) {
        int p = m * 16 + fr; if (p > 109) p = 109;
        int h = p / 11, w = p - h * 11;
        const int bm = ab + h * A1_RS + w * A1_PS;
        f32x4 acc0 = {0.f, 0.f, 0.f, 0.f}, acc1 = {0.f, 0.f, 0.f, 0.f};
        bf16x8v a;
        a = *(const bf16x8v*)&a1_s[bm + d0];
        acc0 = __builtin_amdgcn_mfma_f32_16x16x32_bf16(a, bfrag[0][0], acc0, 0, 0, 0);
        acc1 = __builtin_amdgcn_mfma_f32_16x16x32_bf16(a, bfrag[0][1], acc1, 0, 0, 0);
        a = *(const bf16x8v*)&a1_s[bm + d1];
        acc0 = __builtin_amdgcn_mfma_f32_16x16x32_bf16(a, bfrag[1][0], acc0, 0, 0, 0);
        acc1 = __builtin_amdgcn_mfma_f32_16x16x32_bf16(a, bfrag[1][1], acc1, 0, 0, 0);
        a = *(const bf16x8v*)&a1_s[bm + d2];
        acc0 = __builtin_amdgcn_mfma_f32_16x16x32_bf16(a, bfrag[2][0], acc0, 0, 0, 0);
        acc1 = __builtin_amdgcn_mfma_f32_16x16x32_bf16(a, bfrag[2][1], acc1, 0, 0, 0);
        a = *(const bf16x8v*)&a1_s[bm + d3];
        acc0 = __builtin_amdgcn_mfma_f32_16x16x32_bf16(a, bfrag[3][0], acc0, 0, 0, 0);
        acc1 = __builtin_amdgcn_mfma_f32_16x16x32_bf16(a, bfrag[3][1], acc1, 0, 0, 0);
        a = *(const bf16x8v*)&a1_s[fqh ? (ab + A1_ZS) : (bm + 672 + icb)];
        acc0 = __builtin_amdgcn_mfma_f32_16x16x32_bf16(a, bfrag[4][0], acc0, 0, 0, 0);
        acc1 = __builtin_amdgcn_mfma_f32_16x16x32_bf16(a, bfrag[4][1], acc1, 0, 0, 0);

        bf16x8v ov;
#pragma unroll
        for (int j = 0; j < 4; ++j) {
            bool valid = (m * 16 + fq * 4 + j) < 110;
            float v0 = valid ? fminf(fmaxf(acc0[j], 0.f), 1.f) : 0.f;
            float v1 = valid ? fminf(fmaxf(acc1[j], 0.f), 1.f) : 0.f;
            ov[j]     = (__bf16)v0;
            ov[4 + j] = (__bf16)v1;
        }
        *(bf16x8v*)&a2p[(size_t)(t * 2048 + b) * FC3_K + m * 512 + lane * 8] = ov;
    }
}

// ---------------- fc3: one GEMM [20480 x 3584] * [3584 x 256] ----------
// 128x64 tile, 4 waves, BK=64, 56 K-steps, DOUBLE-buffered LDS with counted
// vmcnt(6) (loads for tile k+1 stay in flight across compute of k).
// grid (4,160): bn fastest so the 4 blocks sharing an A-tile are adjacent.
__global__ __launch_bounds__(256) void fc3_all_k(
    const __hip_bfloat16* __restrict__ A,   // [20480][3584]
    const __hip_bfloat16* __restrict__ W,   // [256][3584]
    __hip_bfloat16* __restrict__ a3)        // [20480][256]
{
    __shared__ __hip_bfloat16 As[2 * 128 * 64];
    __shared__ __hip_bfloat16 Bs[2 * 64 * 64];

    const int tid  = threadIdx.x;
    const int wv   = tid >> 6;
    const int lane = tid & 63;
    const int m0 = blockIdx.y * 128, n0 = blockIdx.x * 64;
    const int wr = wv >> 1, wc = wv & 1;

    const int srow   = lane >> 3;
    const int schunk = lane & 7;
    const int swzc   = schunk ^ srow;

    const int fr = lane & 15;
    const int fq = lane >> 4;

    f32x4 acc[4][2];
#pragma unroll
    for (int mi = 0; mi < 4; ++mi)
#pragma unroll
        for (int ni = 0; ni < 2; ++ni)
            acc[mi][ni] = (f32x4){0.f, 0.f, 0.f, 0.f};

    // stage tile kt into buffer pb (6 global_load_lds of 1 KiB each)
    auto STAGE = [&](int kt, int pb) {
        const int kb = kt * 64;
#pragma unroll
        for (int i = 0; i < 4; ++i) {
            const int tr = wv * 32 + i * 8;
            const __hip_bfloat16* srcA =
                A + (size_t)(m0 + tr + srow) * FC3_K + kb + swzc * 8;
            __builtin_amdgcn_global_load_lds(
                (const __attribute__((address_space(1))) void*)srcA,
                (__attribute__((address_space(3))) void*)&As[pb * 8192 + tr * 64], 16, 0, 0);
        }
#pragma unroll
        for (int i = 0; i < 2; ++i) {
            const int tr = wv * 16 + i * 8;
            const __hip_bfloat16* srcB =
                W + (size_t)(n0 + tr + srow) * FC3_K + kb + swzc * 8;
            __builtin_amdgcn_global_load_lds(
                (const __attribute__((address_space(1))) void*)srcB,
                (__attribute__((address_space(3))) void*)&Bs[pb * 4096 + tr * 64], 16, 0, 0);
        }
    };

    STAGE(0, 0);
    int cur = 0;
    for (int kt = 0; kt < 56; ++kt) {
        if (kt + 1 < 56) {
            STAGE(kt + 1, cur ^ 1);
            asm volatile("s_waitcnt vmcnt(6)" ::: "memory");   // current tile landed
        } else {
            asm volatile("s_waitcnt vmcnt(0)" ::: "memory");
        }
        __builtin_amdgcn_s_barrier();

        const __hip_bfloat16* Ab = &As[cur * 8192];
        const __hip_bfloat16* Bb = &Bs[cur * 4096];
#pragma unroll
        for (int kk = 0; kk < 2; ++kk) {
            bf16x8v af[4], bfv[2];
#pragma unroll
            for (int mi = 0; mi < 4; ++mi) {
                const int rr = wr * 64 + mi * 16 + fr;
                const int cc = (kk * 4 + fq) ^ (rr & 7);
                af[mi] = *(const bf16x8v*)&Ab[rr * 64 + cc * 8];
            }
#pragma unroll
            for (int ni = 0; ni < 2; ++ni) {
                const int rr = wc * 32 + ni * 16 + fr;
                const int cc = (kk * 4 + fq) ^ (rr & 7);
                bfv[ni] = *(const bf16x8v*)&Bb[rr * 64 + cc * 8];
            }
#pragma unroll
            for (int mi = 0; mi < 4; ++mi)
#pragma unroll
                for (int ni = 0; ni < 2; ++ni)
                    acc[mi][ni] = __builtin_amdgcn_mfma_f32_16x16x32_bf16(
                        af[mi], bfv[ni], acc[mi][ni], 0, 0, 0);
        }
        __builtin_amdgcn_s_barrier();   // all waves done reading buf cur
        cur ^= 1;
    }

#pragma unroll
    for (int mi = 0; mi < 4; ++mi)
#pragma unroll
        for (int ni = 0; ni < 2; ++ni)
#pragma unroll
            for (int j = 0; j < 4; ++j) {
                int row = m0 + wr * 64 + mi * 16 + fq * 4 + j;
                int col = n0 + wc * 32 + ni * 16 + fr;
                float v = fminf(fmaxf(acc[mi][ni][j], 0.f), 1.f);
                a3[(size_t)row * 256 + col] = __float2bfloat16(v);
            }
}

// ---------------- MGU all steps + fc5, one kernel ----------------
__global__ __launch_bounds__(256, 1) void mgu_all_k(
    const __hip_bfloat16* __restrict__ a3,  // [10*2048][256]
    const __hip_bfloat16* __restrict__ wfi, const __hip_bfloat16* __restrict__ wfh,
    const float* __restrict__ w5, float* __restrict__ out)
{
    __shared__ __hip_bfloat16 a3_s[16 * 256];
    __shared__ __hip_bfloat16 hq_s[16 * 64];
    __shared__ float hx_s[16 * 64];
    __shared__ float w5_s[7 * 64];

    const int tid = threadIdx.x;
    const int wv  = tid >> 6, lane = tid & 63;
    const int fr  = lane & 15, fq = lane >> 4;
    const int b0  = blockIdx.x * 16;
    const int ntf = wv, ntn = wv + 4;

    bf16x8v wiF[8][2], wiN[8][2], whF[2][2], whN[2][2];
#pragma unroll
    for (int kt = 0; kt < 8; ++kt)
#pragma unroll
        for (int hl = 0; hl < 2; ++hl) {
            wiF[kt][hl] = *(const bf16x8v*)&wfi[(((ntf * 8 + kt) * 2 + hl) * 64 + lane) * 8];
            wiN[kt][hl] = *(const bf16x8v*)&wfi[(((ntn * 8 + kt) * 2 + hl) * 64 + lane) * 8];
        }
#pragma unroll
    for (int kt = 0; kt < 2; ++kt)
#pragma unroll
        for (int hl = 0; hl < 2; ++hl) {
            whF[kt][hl] = *(const bf16x8v*)&wfh[(((ntf * 2 + kt) * 2 + hl) * 64 + lane) * 8];
            whN[kt][hl] = *(const bf16x8v*)&wfh[(((ntn * 2 + kt) * 2 + hl) * 64 + lane) * 8];
        }

    for (int i = tid; i < 16 * 64; i += 256) hx_s[i] = 0.f;
    for (int i = tid; i < 7 * 64; i += 256) w5_s[i] = w5[i];
    __syncthreads();

    for (int t = 0; t < 10; ++t) {
#pragma unroll
        for (int pass = 0; pass < 2; ++pass) {
            int i = pass * 256 + tid;
            int r = i >> 5, cq = i & 31;
            bf16x8v v = *(const bf16x8v*)&a3[((size_t)(t * 2048 + b0 + r)) * 256 + cq * 8];
            *(bf16x8v*)&a3_s[r * 256 + ((cq ^ (r & 7)) * 8)] = v;
        }
#pragma unroll
        for (int pass = 0; pass < 4; ++pass) {
            int i = pass * 256 + tid;
            int r = i >> 6, c = i & 63;
            float v = hx_s[r * 64 + c];
            v = fminf(fmaxf(v, -1.f), 1.f);
            v = rintf(v * 128.f) * 0.0078125f;
            hq_s[r * 64 + (((c >> 3) ^ (r & 7)) << 3) + (c & 7)] = __float2bfloat16(v);
        }
        __syncthreads();

        f32x4 accF  = {0.f, 0.f, 0.f, 0.f};
        f32x4 accNi = {0.f, 0.f, 0.f, 0.f};
        f32x4 accNh = {0.f, 0.f, 0.f, 0.f};
#pragma unroll
        for (int kt = 0; kt < 8; ++kt) {
            bf16x8v a = *(const bf16x8v*)&a3_s[fr * 256 + (((kt * 4 + fq) ^ (fr & 7)) * 8)];
            accF  = __builtin_amdgcn_mfma_f32_16x16x32_bf16(a, wiF[kt][0], accF, 0, 0, 0);
            accF  = __builtin_amdgcn_mfma_f32_16x16x32_bf16(a, wiF[kt][1], accF, 0, 0, 0);
            accNi = __builtin_amdgcn_mfma_f32_16x16x32_bf16(a, wiN[kt][0], accNi, 0, 0, 0);
            accNi = __builtin_amdgcn_mfma_f32_16x16x32_bf16(a, wiN[kt][1], accNi, 0, 0, 0);
        }
#pragma unroll
        for (int kt = 0; kt < 2; ++kt) {
            bf16x8v a = *(const bf16x8v*)&hq_s[fr * 64 + (((kt * 4 + fq) ^ (fr & 7)) * 8)];
            accF  = __builtin_amdgcn_mfma_f32_16x16x32_bf16(a, whF[kt][0], accF, 0, 0, 0);
            accF  = __builtin_amdgcn_mfma_f32_16x16x32_bf16(a, whF[kt][1], accF, 0, 0, 0);
            accNh = __builtin_amdgcn_mfma_f32_16x16x32_bf16(a, whN[kt][0], accNh, 0, 0, 0);
            accNh = __builtin_amdgcn_mfma_f32_16x16x32_bf16(a, whN[kt][1], accNh, 0, 0, 0);
        }

        const int j5 = wv * 16 + fr;
#pragma unroll
        for (int j = 0; j < 4; ++j) {
            int b = fq * 4 + j;
            float f = fminf(fmaxf(0.5f * accF[j] + 0.5f, 0.f), 1.f);
            float n = fminf(fmaxf(accNi[j] + f * accNh[j], -1.f), 1.f);
            float hq = __bfloat162float(
                hq_s[b * 64 + ((((j5) >> 3) ^ (b & 7)) << 3) + (j5 & 7)]);
            hx_s[b * 64 + j5] = (1.f - f) * n + f * hq;
        }
        __syncthreads();
    }

    if (tid < 112) {
        int b = tid / 7, c = tid % 7;
        float acc = 0.f;
#pragma unroll
        for (int k = 0; k < 64; ++k) acc += hx_s[b * 64 + k] * w5_s[c * 64 + k];
        out[(size_t)(b0 + b) * 7 + c] = acc;
    }
}

extern "C" void kernel_launch(void* const* d_in, const int* in_sizes, int n_in,
                              void* d_out, int out_size, void* d_ws, size_t ws_size,
                              hipStream_t stream)
{
    const float* x    = (const float*)d_in[0];
    const float* w1   = (const float*)d_in[1];
    const float* w2   = (const float*)d_in[2];
    const float* fc3w = (const float*)d_in[3];
    const float* wih  = (const float*)d_in[4];
    const float* whh  = (const float*)d_in[5];
    const float* fc5w = (const float*)d_in[6];
    float* out = (float*)d_out;

    char* ws = (char*)d_ws;
    __hip_bfloat16* a2p = (__hip_bfloat16*)ws;                     // 146,800,640
    __hip_bfloat16* a3  = (__hip_bfloat16*)(ws + 146800640);       //  10,485,760
    __hip_bfloat16* w3p = (__hip_bfloat16*)(ws + 157286400);       //   1,835,008
    __hip_bfloat16* w2p = (__hip_bfloat16*)(ws + 159121408);       //      10,240
    __hip_bfloat16* wfi = (__hip_bfloat16*)(ws + 159131648);       //     131,072
    __hip_bfloat16* wfh = (__hip_bfloat16*)(ws + 159262720);       //      32,768

    cvt_all_k<<<3924, 256, 0, stream>>>(fc3w, w2, wih, whh, w3p, w2p, wfi, wfh);
    conv_all_k<<<5120, 256, 0, stream>>>(x, w1, w2p, a2p);
    fc3_all_k<<<dim3(4, 160), 256, 0, stream>>>(a2p, w3p, a3);
    mgu_all_k<<<128, 256, 0, stream>>>(a3, wfi, wfh, fc5w, out);
}

// Round 7
// 113.174 us; speedup vs baseline: 1.2972x; 1.2972x over previous
//
#include <hip/hip_runtime.h>
#include <hip/hip_bf16.h>
#include <cstdint>
#include <cstddef>

// ---------------------------------------------------------------------------
// R7: fc3 keeps the R6 double-buffered counted-vmcnt pipeline but adds an
//     XCD-aware block remap: the 4 blocks sharing one 128-row A-panel all
//     land on the SAME XCD (panel reuse via private L2, not L3) and dispatch
//     8 apart. conv/mgu/cvt unchanged from R6.
// ---------------------------------------------------------------------------

typedef __bf16 bf16x8v __attribute__((ext_vector_type(8)));
typedef float  f32x4   __attribute__((ext_vector_type(4)));

#define WAVE_FENCE() asm volatile("s_waitcnt lgkmcnt(0)" ::: "memory")

#define A1_PS 24
#define A1_RS (13 * A1_PS)          // 312
#define A1_ZS (12 * A1_RS)          // zero slot
#define A1_BS 3776                  // per-batch elems (7552 B)
#define XQ_RS 20                    // padded row stride (floats), 16B-aligned
#define XQ_BS 256

#define FC3_K 3584                  // permuted/padded K (7 Mtiles * 512)

// ---------------- all weight converts in one launch ----------------
__global__ __launch_bounds__(256) void cvt_all_k(
    const float* __restrict__ fc3w, const float* __restrict__ w2g,
    const float* __restrict__ wih,  const float* __restrict__ whh,
    __hip_bfloat16* __restrict__ w3p, __hip_bfloat16* __restrict__ w2p,
    __hip_bfloat16* __restrict__ wfi, __hip_bfloat16* __restrict__ wfh)
{
    int bid = blockIdx.x;
    if (bid < 3584) {
        int idx = bid * 256 + threadIdx.x;
        int n = idx / FC3_K, kp = idx % FC3_K;
        int mt = kp >> 9, r = kp & 511;
        int fq = r >> 7, col = (r >> 3) & 15, nt = (r >> 2) & 1, j = r & 3;
        int pixel = mt * 16 + fq * 4 + j, oc = nt * 16 + col;
        float v = (pixel < 110) ? fc3w[n * 3520 + oc * 110 + pixel] : 0.f;
        w3p[idx] = __float2bfloat16(v);
    } else if (bid < 3604) {
        int idx = (bid - 3584) * 256 + threadIdx.x;
        if (idx < 5120) {
            int oc = idx / 160, k = idx % 160;
            int koff = k >> 4, ic = k & 15;
            float v = (koff < 9) ? w2g[(oc * 16 + ic) * 9 + koff] : 0.f;
            w2p[idx] = __float2bfloat16(v);
        }
    } else if (bid < 3860) {
        int idx = (bid - 3604) * 256 + threadIdx.x;   // < 65536
        int e = idx & 7, lane = (idx >> 3) & 63, hl = (idx >> 9) & 1;
        int kt = (idx >> 10) & 7, nt = (idx >> 13) & 7;
        int gate = nt * 16 + (lane & 15);
        int k = kt * 32 + (lane >> 4) * 8 + e;
        float v = wih[gate * 256 + k];
        __hip_bfloat16 hi = __float2bfloat16(v);
        wfi[idx] = hl ? __float2bfloat16(v - __bfloat162float(hi)) : hi;
    } else {
        int idx = (bid - 3860) * 256 + threadIdx.x;   // < 16384
        int e = idx & 7, lane = (idx >> 3) & 63, hl = (idx >> 9) & 1;
        int kt = (idx >> 10) & 1, nt = (idx >> 11) & 7;
        int gate = nt * 16 + (lane & 15);
        int k = kt * 32 + (lane >> 4) * 8 + e;
        float v = whh[gate * 64 + k];
        __hip_bfloat16 hi = __float2bfloat16(v);
        wfh[idx] = hl ? __float2bfloat16(v - __bfloat162float(hi)) : hi;
    }
}

// ---------------- all-steps fused quant + conv1 + conv2 ----------------
__global__ __launch_bounds__(256) void conv_all_k(
    const float* __restrict__ x, const float* __restrict__ w1g,
    const __hip_bfloat16* __restrict__ w2p,
    __hip_bfloat16* __restrict__ a2p)
{
    __shared__ __hip_bfloat16 a1_s[4 * A1_BS];
    __shared__ float xq_s[4 * XQ_BS];

    const int tid  = threadIdx.x;
    const int wv   = tid >> 6, lane = tid & 63;
    const int t    = blockIdx.x >> 9;
    const int b    = (blockIdx.x & 511) * 4 + wv;
    const int ab   = wv * A1_BS;
    const int xb   = wv * XQ_BS;

    const int fr  = lane & 15, fq = lane >> 4;
    const int fqh = fq >> 1,  icb = (fq & 1) * 8;

    bf16x8v bfrag[5][2];
#pragma unroll
    for (int kt = 0; kt < 5; ++kt)
#pragma unroll
        for (int nt = 0; nt < 2; ++nt)
            bfrag[kt][nt] = *(const bf16x8v*)&w2p[(nt * 16 + fr) * 160 + kt * 32 + fq * 8];

    const int ocp = lane & 7, rs = lane >> 3;
    float w1a[9], w1b[9];
#pragma unroll
    for (int k = 0; k < 9; ++k) {
        w1a[k] = w1g[(2 * ocp) * 9 + k];
        w1b[k] = w1g[(2 * ocp + 1) * 9 + k];
    }

    {
        bf16x8v z = {};
#pragma unroll
        for (int i = 0; i < 8; ++i) {
            int c = lane + i * 64;
            if (c < A1_BS / 8) *(bf16x8v*)&a1_s[ab + c * 8] = z;
        }
        float4 zf = {0.f, 0.f, 0.f, 0.f};
        *(float4*)&xq_s[xb + lane * 4] = zf;
    }
    WAVE_FENCE();

#pragma unroll
    for (int pass = 0; pass < 2; ++pass) {
        int p = pass * 64 + lane;
        if (p < 110) {
            float xv = x[(size_t)b * 1100 + t * 110 + p];
            xv = fminf(fmaxf(xv, -1.f), 1.f);
            xv = rintf(xv * 128.f) * 0.0078125f;
            int h = p / 11, w = p - h * 11;
            xq_s[xb + (h + 1) * XQ_RS + (w + 1)] = xv;
        }
    }
    WAVE_FENCE();

#pragma unroll
    for (int pass = 0; pass < 2; ++pass) {
        const int hr = pass == 0 ? rs : rs + 8;
        if (hr < 10) {
            float acc0[11], acc1[11];
#pragma unroll
            for (int w = 0; w < 11; ++w) { acc0[w] = 0.f; acc1[w] = 0.f; }
#pragma unroll
            for (int dr = 0; dr < 3; ++dr) {
                float xr[16];
                const float* row = &xq_s[xb + (hr + dr) * XQ_RS];
#pragma unroll
                for (int j = 0; j < 4; ++j)
                    *(float4*)&xr[j * 4] = *(const float4*)&row[j * 4];
#pragma unroll
                for (int dc = 0; dc < 3; ++dc) {
                    float wa = w1a[dr * 3 + dc], wb = w1b[dr * 3 + dc];
#pragma unroll
                    for (int w = 0; w < 11; ++w) {
                        acc0[w] += xr[w + dc] * wa;
                        acc1[w] += xr[w + dc] * wb;
                    }
                }
            }
#pragma unroll
            for (int w = 0; w < 11; ++w) {
                __hip_bfloat162 pr;
                pr.x = __float2bfloat16(fminf(fmaxf(acc0[w], 0.f), 1.f));
                pr.y = __float2bfloat16(fminf(fmaxf(acc1[w], 0.f), 1.f));
                *(__hip_bfloat162*)&a1_s[ab + (hr + 1) * A1_RS + (w + 1) * A1_PS + 2 * ocp] = pr;
            }
        }
    }
    WAVE_FENCE();

    const int d0 = fqh * 24 + icb;
    const int d1 = (fqh ? 312 : 48) + icb;
    const int d2 = 336 + fqh * 24 + icb;
    const int d3 = 624 + fqh * 24 + icb;

#pragma unroll
    for (int m = 0; m < 7; ++m) {
        int p = m * 16 + fr; if (p > 109) p = 109;
        int h = p / 11, w = p - h * 11;
        const int bm = ab + h * A1_RS + w * A1_PS;
        f32x4 acc0 = {0.f, 0.f, 0.f, 0.f}, acc1 = {0.f, 0.f, 0.f, 0.f};
        bf16x8v a;
        a = *(const bf16x8v*)&a1_s[bm + d0];
        acc0 = __builtin_amdgcn_mfma_f32_16x16x32_bf16(a, bfrag[0][0], acc0, 0, 0, 0);
        acc1 = __builtin_amdgcn_mfma_f32_16x16x32_bf16(a, bfrag[0][1], acc1, 0, 0, 0);
        a = *(const bf16x8v*)&a1_s[bm + d1];
        acc0 = __builtin_amdgcn_mfma_f32_16x16x32_bf16(a, bfrag[1][0], acc0, 0, 0, 0);
        acc1 = __builtin_amdgcn_mfma_f32_16x16x32_bf16(a, bfrag[1][1], acc1, 0, 0, 0);
        a = *(const bf16x8v*)&a1_s[bm + d2];
        acc0 = __builtin_amdgcn_mfma_f32_16x16x32_bf16(a, bfrag[2][0], acc0, 0, 0, 0);
        acc1 = __builtin_amdgcn_mfma_f32_16x16x32_bf16(a, bfrag[2][1], acc1, 0, 0, 0);
        a = *(const bf16x8v*)&a1_s[bm + d3];
        acc0 = __builtin_amdgcn_mfma_f32_16x16x32_bf16(a, bfrag[3][0], acc0, 0, 0, 0);
        acc1 = __builtin_amdgcn_mfma_f32_16x16x32_bf16(a, bfrag[3][1], acc1, 0, 0, 0);
        a = *(const bf16x8v*)&a1_s[fqh ? (ab + A1_ZS) : (bm + 672 + icb)];
        acc0 = __builtin_amdgcn_mfma_f32_16x16x32_bf16(a, bfrag[4][0], acc0, 0, 0, 0);
        acc1 = __builtin_amdgcn_mfma_f32_16x16x32_bf16(a, bfrag[4][1], acc1, 0, 0, 0);

        bf16x8v ov;
#pragma unroll
        for (int j = 0; j < 4; ++j) {
            bool valid = (m * 16 + fq * 4 + j) < 110;
            float v0 = valid ? fminf(fmaxf(acc0[j], 0.f), 1.f) : 0.f;
            float v1 = valid ? fminf(fmaxf(acc1[j], 0.f), 1.f) : 0.f;
            ov[j]     = (__bf16)v0;
            ov[4 + j] = (__bf16)v1;
        }
        *(bf16x8v*)&a2p[(size_t)(t * 2048 + b) * FC3_K + m * 512 + lane * 8] = ov;
    }
}

// ---------------- fc3: one GEMM [20480 x 3584] * [3584 x 256] ----------
// 128x64 tile, 4 waves, BK=64, 56 K-steps, double-buffered counted vmcnt(6).
// XCD-aware remap: grid 640 1-D; d&7 = XCD; the 4 bn-sharers of an A-panel
// are consecutive slots on ONE XCD (share via private L2), dispatched 8 apart.
__global__ __launch_bounds__(256) void fc3_all_k(
    const __hip_bfloat16* __restrict__ A,   // [20480][3584]
    const __hip_bfloat16* __restrict__ W,   // [256][3584]
    __hip_bfloat16* __restrict__ a3)        // [20480][256]
{
    __shared__ __hip_bfloat16 As[2 * 128 * 64];
    __shared__ __hip_bfloat16 Bs[2 * 64 * 64];

    const int tid  = threadIdx.x;
    const int wv   = tid >> 6;
    const int lane = tid & 63;

    const int d    = blockIdx.x;            // 0..639
    const int xcd  = d & 7;
    const int slot = d >> 3;                // 0..79 within XCD
    const int n0   = (slot & 3) * 64;       // bn
    const int m0   = (xcd * 20 + (slot >> 2)) * 128;   // bm 0..159

    const int wr = wv >> 1, wc = wv & 1;

    const int srow   = lane >> 3;
    const int schunk = lane & 7;
    const int swzc   = schunk ^ srow;

    const int fr = lane & 15;
    const int fq = lane >> 4;

    f32x4 acc[4][2];
#pragma unroll
    for (int mi = 0; mi < 4; ++mi)
#pragma unroll
        for (int ni = 0; ni < 2; ++ni)
            acc[mi][ni] = (f32x4){0.f, 0.f, 0.f, 0.f};

    auto STAGE = [&](int kt, int pb) {
        const int kb = kt * 64;
#pragma unroll
        for (int i = 0; i < 4; ++i) {
            const int tr = wv * 32 + i * 8;
            const __hip_bfloat16* srcA =
                A + (size_t)(m0 + tr + srow) * FC3_K + kb + swzc * 8;
            __builtin_amdgcn_global_load_lds(
                (const __attribute__((address_space(1))) void*)srcA,
                (__attribute__((address_space(3))) void*)&As[pb * 8192 + tr * 64], 16, 0, 0);
        }
#pragma unroll
        for (int i = 0; i < 2; ++i) {
            const int tr = wv * 16 + i * 8;
            const __hip_bfloat16* srcB =
                W + (size_t)(n0 + tr + srow) * FC3_K + kb + swzc * 8;
            __builtin_amdgcn_global_load_lds(
                (const __attribute__((address_space(1))) void*)srcB,
                (__attribute__((address_space(3))) void*)&Bs[pb * 4096 + tr * 64], 16, 0, 0);
        }
    };

    STAGE(0, 0);
    int cur = 0;
    for (int kt = 0; kt < 56; ++kt) {
        if (kt + 1 < 56) {
            STAGE(kt + 1, cur ^ 1);
            asm volatile("s_waitcnt vmcnt(6)" ::: "memory");
        } else {
            asm volatile("s_waitcnt vmcnt(0)" ::: "memory");
        }
        __builtin_amdgcn_s_barrier();

        const __hip_bfloat16* Ab = &As[cur * 8192];
        const __hip_bfloat16* Bb = &Bs[cur * 4096];
#pragma unroll
        for (int kk = 0; kk < 2; ++kk) {
            bf16x8v af[4], bfv[2];
#pragma unroll
            for (int mi = 0; mi < 4; ++mi) {
                const int rr = wr * 64 + mi * 16 + fr;
                const int cc = (kk * 4 + fq) ^ (rr & 7);
                af[mi] = *(const bf16x8v*)&Ab[rr * 64 + cc * 8];
            }
#pragma unroll
            for (int ni = 0; ni < 2; ++ni) {
                const int rr = wc * 32 + ni * 16 + fr;
                const int cc = (kk * 4 + fq) ^ (rr & 7);
                bfv[ni] = *(const bf16x8v*)&Bb[rr * 64 + cc * 8];
            }
#pragma unroll
            for (int mi = 0; mi < 4; ++mi)
#pragma unroll
                for (int ni = 0; ni < 2; ++ni)
                    acc[mi][ni] = __builtin_amdgcn_mfma_f32_16x16x32_bf16(
                        af[mi], bfv[ni], acc[mi][ni], 0, 0, 0);
        }
        __builtin_amdgcn_s_barrier();
        cur ^= 1;
    }

#pragma unroll
    for (int mi = 0; mi < 4; ++mi)
#pragma unroll
        for (int ni = 0; ni < 2; ++ni)
#pragma unroll
            for (int j = 0; j < 4; ++j) {
                int row = m0 + wr * 64 + mi * 16 + fq * 4 + j;
                int col = n0 + wc * 32 + ni * 16 + fr;
                float v = fminf(fmaxf(acc[mi][ni][j], 0.f), 1.f);
                a3[(size_t)row * 256 + col] = __float2bfloat16(v);
            }
}

// ---------------- MGU all steps + fc5, one kernel ----------------
__global__ __launch_bounds__(256, 1) void mgu_all_k(
    const __hip_bfloat16* __restrict__ a3,  // [10*2048][256]
    const __hip_bfloat16* __restrict__ wfi, const __hip_bfloat16* __restrict__ wfh,
    const float* __restrict__ w5, float* __restrict__ out)
{
    __shared__ __hip_bfloat16 a3_s[16 * 256];
    __shared__ __hip_bfloat16 hq_s[16 * 64];
    __shared__ float hx_s[16 * 64];
    __shared__ float w5_s[7 * 64];

    const int tid = threadIdx.x;
    const int wv  = tid >> 6, lane = tid & 63;
    const int fr  = lane & 15, fq = lane >> 4;
    const int b0  = blockIdx.x * 16;
    const int ntf = wv, ntn = wv + 4;

    bf16x8v wiF[8][2], wiN[8][2], whF[2][2], whN[2][2];
#pragma unroll
    for (int kt = 0; kt < 8; ++kt)
#pragma unroll
        for (int hl = 0; hl < 2; ++hl) {
            wiF[kt][hl] = *(const bf16x8v*)&wfi[(((ntf * 8 + kt) * 2 + hl) * 64 + lane) * 8];
            wiN[kt][hl] = *(const bf16x8v*)&wfi[(((ntn * 8 + kt) * 2 + hl) * 64 + lane) * 8];
        }
#pragma unroll
    for (int kt = 0; kt < 2; ++kt)
#pragma unroll
        for (int hl = 0; hl < 2; ++hl) {
            whF[kt][hl] = *(const bf16x8v*)&wfh[(((ntf * 2 + kt) * 2 + hl) * 64 + lane) * 8];
            whN[kt][hl] = *(const bf16x8v*)&wfh[(((ntn * 2 + kt) * 2 + hl) * 64 + lane) * 8];
        }

    for (int i = tid; i < 16 * 64; i += 256) hx_s[i] = 0.f;
    for (int i = tid; i < 7 * 64; i += 256) w5_s[i] = w5[i];
    __syncthreads();

    for (int t = 0; t < 10; ++t) {
#pragma unroll
        for (int pass = 0; pass < 2; ++pass) {
            int i = pass * 256 + tid;
            int r = i >> 5, cq = i & 31;
            bf16x8v v = *(const bf16x8v*)&a3[((size_t)(t * 2048 + b0 + r)) * 256 + cq * 8];
            *(bf16x8v*)&a3_s[r * 256 + ((cq ^ (r & 7)) * 8)] = v;
        }
#pragma unroll
        for (int pass = 0; pass < 4; ++pass) {
            int i = pass * 256 + tid;
            int r = i >> 6, c = i & 63;
            float v = hx_s[r * 64 + c];
            v = fminf(fmaxf(v, -1.f), 1.f);
            v = rintf(v * 128.f) * 0.0078125f;
            hq_s[r * 64 + (((c >> 3) ^ (r & 7)) << 3) + (c & 7)] = __float2bfloat16(v);
        }
        __syncthreads();

        f32x4 accF  = {0.f, 0.f, 0.f, 0.f};
        f32x4 accNi = {0.f, 0.f, 0.f, 0.f};
        f32x4 accNh = {0.f, 0.f, 0.f, 0.f};
#pragma unroll
        for (int kt = 0; kt < 8; ++kt) {
            bf16x8v a = *(const bf16x8v*)&a3_s[fr * 256 + (((kt * 4 + fq) ^ (fr & 7)) * 8)];
            accF  = __builtin_amdgcn_mfma_f32_16x16x32_bf16(a, wiF[kt][0], accF, 0, 0, 0);
            accF  = __builtin_amdgcn_mfma_f32_16x16x32_bf16(a, wiF[kt][1], accF, 0, 0, 0);
            accNi = __builtin_amdgcn_mfma_f32_16x16x32_bf16(a, wiN[kt][0], accNi, 0, 0, 0);
            accNi = __builtin_amdgcn_mfma_f32_16x16x32_bf16(a, wiN[kt][1], accNi, 0, 0, 0);
        }
#pragma unroll
        for (int kt = 0; kt < 2; ++kt) {
            bf16x8v a = *(const bf16x8v*)&hq_s[fr * 64 + (((kt * 4 + fq) ^ (fr & 7)) * 8)];
            accF  = __builtin_amdgcn_mfma_f32_16x16x32_bf16(a, whF[kt][0], accF, 0, 0, 0);
            accF  = __builtin_amdgcn_mfma_f32_16x16x32_bf16(a, whF[kt][1], accF, 0, 0, 0);
            accNh = __builtin_amdgcn_mfma_f32_16x16x32_bf16(a, whN[kt][0], accNh, 0, 0, 0);
            accNh = __builtin_amdgcn_mfma_f32_16x16x32_bf16(a, whN[kt][1], accNh, 0, 0, 0);
        }

        const int j5 = wv * 16 + fr;
#pragma unroll
        for (int j = 0; j < 4; ++j) {
            int b = fq * 4 + j;
            float f = fminf(fmaxf(0.5f * accF[j] + 0.5f, 0.f), 1.f);
            float n = fminf(fmaxf(accNi[j] + f * accNh[j], -1.f), 1.f);
            float hq = __bfloat162float(
                hq_s[b * 64 + ((((j5) >> 3) ^ (b & 7)) << 3) + (j5 & 7)]);
            hx_s[b * 64 + j5] = (1.f - f) * n + f * hq;
        }
        __syncthreads();
    }

    if (tid < 112) {
        int b = tid / 7, c = tid % 7;
        float acc = 0.f;
#pragma unroll
        for (int k = 0; k < 64; ++k) acc += hx_s[b * 64 + k] * w5_s[c * 64 + k];
        out[(size_t)(b0 + b) * 7 + c] = acc;
    }
}

extern "C" void kernel_launch(void* const* d_in, const int* in_sizes, int n_in,
                              void* d_out, int out_size, void* d_ws, size_t ws_size,
                              hipStream_t stream)
{
    const float* x    = (const float*)d_in[0];
    const float* w1   = (const float*)d_in[1];
    const float* w2   = (const float*)d_in[2];
    const float* fc3w = (const float*)d_in[3];
    const float* wih  = (const float*)d_in[4];
    const float* whh  = (const float*)d_in[5];
    const float* fc5w = (const float*)d_in[6];
    float* out = (float*)d_out;

    char* ws = (char*)d_ws;
    __hip_bfloat16* a2p = (__hip_bfloat16*)ws;                     // 146,800,640
    __hip_bfloat16* a3  = (__hip_bfloat16*)(ws + 146800640);       //  10,485,760
    __hip_bfloat16* w3p = (__hip_bfloat16*)(ws + 157286400);       //   1,835,008
    __hip_bfloat16* w2p = (__hip_bfloat16*)(ws + 159121408);       //      10,240
    __hip_bfloat16* wfi = (__hip_bfloat16*)(ws + 159131648);       //     131,072
    __hip_bfloat16* wfh = (__hip_bfloat16*)(ws + 159262720);       //      32,768

    cvt_all_k<<<3924, 256, 0, stream>>>(fc3w, w2, wih, whh, w3p, w2p, wfi, wfh);
    conv_all_k<<<5120, 256, 0, stream>>>(x, w1, w2p, a2p);
    fc3_all_k<<<640, 256, 0, stream>>>(a2p, w3p, a3);
    mgu_all_k<<<128, 256, 0, stream>>>(a3, wfi, wfh, fc5w, out);
}

// Round 8
// 111.222 us; speedup vs baseline: 1.3200x; 1.0175x over previous
//
#include <hip/hip_runtime.h>
#include <hip/hip_bf16.h>
#include <cstdint>
#include <cstddef>

// ---------------------------------------------------------------------------
// R8: fc3 K-loop rebuilt: static x2-unrolled double buffer (compile-time LDS
//     bases), hoisted global src pointers (+64/stage), precomputed ds_read
//     offsets, depth-2 prefetch (12 loads in flight, vmcnt(6)). XCD remap
//     kept from R7. conv/mgu/cvt unchanged.
// ---------------------------------------------------------------------------

typedef __bf16 bf16x8v __attribute__((ext_vector_type(8)));
typedef float  f32x4   __attribute__((ext_vector_type(4)));

#define WAVE_FENCE() asm volatile("s_waitcnt lgkmcnt(0)" ::: "memory")

#define A1_PS 24
#define A1_RS (13 * A1_PS)          // 312
#define A1_ZS (12 * A1_RS)          // zero slot
#define A1_BS 3776                  // per-batch elems (7552 B)
#define XQ_RS 20
#define XQ_BS 256

#define FC3_K 3584                  // permuted/padded K (7 Mtiles * 512)

// ---------------- all weight converts in one launch ----------------
__global__ __launch_bounds__(256) void cvt_all_k(
    const float* __restrict__ fc3w, const float* __restrict__ w2g,
    const float* __restrict__ wih,  const float* __restrict__ whh,
    __hip_bfloat16* __restrict__ w3p, __hip_bfloat16* __restrict__ w2p,
    __hip_bfloat16* __restrict__ wfi, __hip_bfloat16* __restrict__ wfh)
{
    int bid = blockIdx.x;
    if (bid < 3584) {
        int idx = bid * 256 + threadIdx.x;
        int n = idx / FC3_K, kp = idx % FC3_K;
        int mt = kp >> 9, r = kp & 511;
        int fq = r >> 7, col = (r >> 3) & 15, nt = (r >> 2) & 1, j = r & 3;
        int pixel = mt * 16 + fq * 4 + j, oc = nt * 16 + col;
        float v = (pixel < 110) ? fc3w[n * 3520 + oc * 110 + pixel] : 0.f;
        w3p[idx] = __float2bfloat16(v);
    } else if (bid < 3604) {
        int idx = (bid - 3584) * 256 + threadIdx.x;
        if (idx < 5120) {
            int oc = idx / 160, k = idx % 160;
            int koff = k >> 4, ic = k & 15;
            float v = (koff < 9) ? w2g[(oc * 16 + ic) * 9 + koff] : 0.f;
            w2p[idx] = __float2bfloat16(v);
        }
    } else if (bid < 3860) {
        int idx = (bid - 3604) * 256 + threadIdx.x;   // < 65536
        int e = idx & 7, lane = (idx >> 3) & 63, hl = (idx >> 9) & 1;
        int kt = (idx >> 10) & 7, nt = (idx >> 13) & 7;
        int gate = nt * 16 + (lane & 15);
        int k = kt * 32 + (lane >> 4) * 8 + e;
        float v = wih[gate * 256 + k];
        __hip_bfloat16 hi = __float2bfloat16(v);
        wfi[idx] = hl ? __float2bfloat16(v - __bfloat162float(hi)) : hi;
    } else {
        int idx = (bid - 3860) * 256 + threadIdx.x;   // < 16384
        int e = idx & 7, lane = (idx >> 3) & 63, hl = (idx >> 9) & 1;
        int kt = (idx >> 10) & 1, nt = (idx >> 11) & 7;
        int gate = nt * 16 + (lane & 15);
        int k = kt * 32 + (lane >> 4) * 8 + e;
        float v = whh[gate * 64 + k];
        __hip_bfloat16 hi = __float2bfloat16(v);
        wfh[idx] = hl ? __float2bfloat16(v - __bfloat162float(hi)) : hi;
    }
}

// ---------------- all-steps fused quant + conv1 + conv2 ----------------
__global__ __launch_bounds__(256) void conv_all_k(
    const float* __restrict__ x, const float* __restrict__ w1g,
    const __hip_bfloat16* __restrict__ w2p,
    __hip_bfloat16* __restrict__ a2p)
{
    __shared__ __hip_bfloat16 a1_s[4 * A1_BS];
    __shared__ float xq_s[4 * XQ_BS];

    const int tid  = threadIdx.x;
    const int wv   = tid >> 6, lane = tid & 63;
    const int t    = blockIdx.x >> 9;
    const int b    = (blockIdx.x & 511) * 4 + wv;
    const int ab   = wv * A1_BS;
    const int xb   = wv * XQ_BS;

    const int fr  = lane & 15, fq = lane >> 4;
    const int fqh = fq >> 1,  icb = (fq & 1) * 8;

    bf16x8v bfrag[5][2];
#pragma unroll
    for (int kt = 0; kt < 5; ++kt)
#pragma unroll
        for (int nt = 0; nt < 2; ++nt)
            bfrag[kt][nt] = *(const bf16x8v*)&w2p[(nt * 16 + fr) * 160 + kt * 32 + fq * 8];

    const int ocp = lane & 7, rs = lane >> 3;
    float w1a[9], w1b[9];
#pragma unroll
    for (int k = 0; k < 9; ++k) {
        w1a[k] = w1g[(2 * ocp) * 9 + k];
        w1b[k] = w1g[(2 * ocp + 1) * 9 + k];
    }

    {
        bf16x8v z = {};
#pragma unroll
        for (int i = 0; i < 8; ++i) {
            int c = lane + i * 64;
            if (c < A1_BS / 8) *(bf16x8v*)&a1_s[ab + c * 8] = z;
        }
        float4 zf = {0.f, 0.f, 0.f, 0.f};
        *(float4*)&xq_s[xb + lane * 4] = zf;
    }
    WAVE_FENCE();

#pragma unroll
    for (int pass = 0; pass < 2; ++pass) {
        int p = pass * 64 + lane;
        if (p < 110) {
            float xv = x[(size_t)b * 1100 + t * 110 + p];
            xv = fminf(fmaxf(xv, -1.f), 1.f);
            xv = rintf(xv * 128.f) * 0.0078125f;
            int h = p / 11, w = p - h * 11;
            xq_s[xb + (h + 1) * XQ_RS + (w + 1)] = xv;
        }
    }
    WAVE_FENCE();

#pragma unroll
    for (int pass = 0; pass < 2; ++pass) {
        const int hr = pass == 0 ? rs : rs + 8;
        if (hr < 10) {
            float acc0[11], acc1[11];
#pragma unroll
            for (int w = 0; w < 11; ++w) { acc0[w] = 0.f; acc1[w] = 0.f; }
#pragma unroll
            for (int dr = 0; dr < 3; ++dr) {
                float xr[16];
                const float* row = &xq_s[xb + (hr + dr) * XQ_RS];
#pragma unroll
                for (int j = 0; j < 4; ++j)
                    *(float4*)&xr[j * 4] = *(const float4*)&row[j * 4];
#pragma unroll
                for (int dc = 0; dc < 3; ++dc) {
                    float wa = w1a[dr * 3 + dc], wb = w1b[dr * 3 + dc];
#pragma unroll
                    for (int w = 0; w < 11; ++w) {
                        acc0[w] += xr[w + dc] * wa;
                        acc1[w] += xr[w + dc] * wb;
                    }
                }
            }
#pragma unroll
            for (int w = 0; w < 11; ++w) {
                __hip_bfloat162 pr;
                pr.x = __float2bfloat16(fminf(fmaxf(acc0[w], 0.f), 1.f));
                pr.y = __float2bfloat16(fminf(fmaxf(acc1[w], 0.f), 1.f));
                *(__hip_bfloat162*)&a1_s[ab + (hr + 1) * A1_RS + (w + 1) * A1_PS + 2 * ocp] = pr;
            }
        }
    }
    WAVE_FENCE();

    const int d0 = fqh * 24 + icb;
    const int d1 = (fqh ? 312 : 48) + icb;
    const int d2 = 336 + fqh * 24 + icb;
    const int d3 = 624 + fqh * 24 + icb;

#pragma unroll
    for (int m = 0; m < 7; ++m) {
        int p = m * 16 + fr; if (p > 109) p = 109;
        int h = p / 11, w = p - h * 11;
        const int bm = ab + h * A1_RS + w * A1_PS;
        f32x4 acc0 = {0.f, 0.f, 0.f, 0.f}, acc1 = {0.f, 0.f, 0.f, 0.f};
        bf16x8v a;
        a = *(const bf16x8v*)&a1_s[bm + d0];
        acc0 = __builtin_amdgcn_mfma_f32_16x16x32_bf16(a, bfrag[0][0], acc0, 0, 0, 0);
        acc1 = __builtin_amdgcn_mfma_f32_16x16x32_bf16(a, bfrag[0][1], acc1, 0, 0, 0);
        a = *(const bf16x8v*)&a1_s[bm + d1];
        acc0 = __builtin_amdgcn_mfma_f32_16x16x32_bf16(a, bfrag[1][0], acc0, 0, 0, 0);
        acc1 = __builtin_amdgcn_mfma_f32_16x16x32_bf16(a, bfrag[1][1], acc1, 0, 0, 0);
        a = *(const bf16x8v*)&a1_s[bm + d2];
        acc0 = __builtin_amdgcn_mfma_f32_16x16x32_bf16(a, bfrag[2][0], acc0, 0, 0, 0);
        acc1 = __builtin_amdgcn_mfma_f32_16x16x32_bf16(a, bfrag[2][1], acc1, 0, 0, 0);
        a = *(const bf16x8v*)&a1_s[bm + d3];
        acc0 = __builtin_amdgcn_mfma_f32_16x16x32_bf16(a, bfrag[3][0], acc0, 0, 0, 0);
        acc1 = __builtin_amdgcn_mfma_f32_16x16x32_bf16(a, bfrag[3][1], acc1, 0, 0, 0);
        a = *(const bf16x8v*)&a1_s[fqh ? (ab + A1_ZS) : (bm + 672 + icb)];
        acc0 = __builtin_amdgcn_mfma_f32_16x16x32_bf16(a, bfrag[4][0], acc0, 0, 0, 0);
        acc1 = __builtin_amdgcn_mfma_f32_16x16x32_bf16(a, bfrag[4][1], acc1, 0, 0, 0);

        bf16x8v ov;
#pragma unroll
        for (int j = 0; j < 4; ++j) {
            bool valid = (m * 16 + fq * 4 + j) < 110;
            float v0 = valid ? fminf(fmaxf(acc0[j], 0.f), 1.f) : 0.f;
            float v1 = valid ? fminf(fmaxf(acc1[j], 0.f), 1.f) : 0.f;
            ov[j]     = (__bf16)v0;
            ov[4 + j] = (__bf16)v1;
        }
        *(bf16x8v*)&a2p[(size_t)(t * 2048 + b) * FC3_K + m * 512 + lane * 8] = ov;
    }
}

// ---------------- fc3: one GEMM [20480 x 3584] * [3584 x 256] ----------
// 128x64 tile, 4 waves, BK=64, 56 K-steps. Static x2-unrolled double buffer,
// depth-2 prefetch (12 loads in flight, vmcnt(6)), hoisted pointers.
// XCD remap: d&7 = XCD; 4 bn-sharers of an A-panel consecutive on one XCD.
__global__ __launch_bounds__(256) void fc3_all_k(
    const __hip_bfloat16* __restrict__ A,   // [20480][3584]
    const __hip_bfloat16* __restrict__ W,   // [256][3584]
    __hip_bfloat16* __restrict__ a3)        // [20480][256]
{
    __shared__ __hip_bfloat16 As[2 * 128 * 64];
    __shared__ __hip_bfloat16 Bs[2 * 64 * 64];

    const int tid  = threadIdx.x;
    const int wv   = tid >> 6;
    const int lane = tid & 63;

    const int d    = blockIdx.x;            // 0..639
    const int xcd  = d & 7;
    const int slot = d >> 3;                // 0..79 within XCD
    const int n0   = (slot & 3) * 64;
    const int m0   = (xcd * 20 + (slot >> 2)) * 128;

    const int wr = wv >> 1, wc = wv & 1;

    const int srow   = lane >> 3;
    const int schunk = lane & 7;
    const int swzc   = schunk ^ srow;

    const int fr = lane & 15;
    const int fq = lane >> 4;

    // hoisted global sources (advanced +64 elements per STAGE)
    const __hip_bfloat16* gA0 = A + (size_t)(m0 + wv * 32 +  0 + srow) * FC3_K + swzc * 8;
    const __hip_bfloat16* gA1 = A + (size_t)(m0 + wv * 32 +  8 + srow) * FC3_K + swzc * 8;
    const __hip_bfloat16* gA2 = A + (size_t)(m0 + wv * 32 + 16 + srow) * FC3_K + swzc * 8;
    const __hip_bfloat16* gA3 = A + (size_t)(m0 + wv * 32 + 24 + srow) * FC3_K + swzc * 8;
    const __hip_bfloat16* gB0 = W + (size_t)(n0 + wv * 16 +  0 + srow) * FC3_K + swzc * 8;
    const __hip_bfloat16* gB1 = W + (size_t)(n0 + wv * 16 +  8 + srow) * FC3_K + swzc * 8;

    // loop-invariant LDS stage destinations (wave-uniform bases)
    __hip_bfloat16* ldsA0 = &As[(wv * 32 +  0) * 64];
    __hip_bfloat16* ldsA1 = &As[(wv * 32 +  8) * 64];
    __hip_bfloat16* ldsA2 = &As[(wv * 32 + 16) * 64];
    __hip_bfloat16* ldsA3 = &As[(wv * 32 + 24) * 64];
    __hip_bfloat16* ldsB0 = &Bs[(wv * 16 +  0) * 64];
    __hip_bfloat16* ldsB1 = &Bs[(wv * 16 +  8) * 64];

#define GLD(src, dst, boff)                                                   \
    __builtin_amdgcn_global_load_lds(                                          \
        (const __attribute__((address_space(1))) void*)(src),                  \
        (__attribute__((address_space(3))) void*)((dst) + (boff)), 16, 0, 0)

// stage one K-tile into buffer b (0/1: A +b*8192, B +b*4096 elems) and advance
#define STAGE(b)                                                               \
    do {                                                                       \
        GLD(gA0, ldsA0, (b) * 8192); GLD(gA1, ldsA1, (b) * 8192);              \
        GLD(gA2, ldsA2, (b) * 8192); GLD(gA3, ldsA3, (b) * 8192);              \
        GLD(gB0, ldsB0, (b) * 4096); GLD(gB1, ldsB1, (b) * 4096);              \
        gA0 += 64; gA1 += 64; gA2 += 64; gA3 += 64; gB0 += 64; gB1 += 64;      \
    } while (0)

    // precomputed ds_read element offsets (within one buffer)
    int aofs[2][4], bofs[2][2];
#pragma unroll
    for (int kk = 0; kk < 2; ++kk) {
#pragma unroll
        for (int mi = 0; mi < 4; ++mi) {
            const int rr = wr * 64 + mi * 16 + fr;
            aofs[kk][mi] = rr * 64 + (((kk * 4 + fq) ^ (rr & 7)) * 8);
        }
#pragma unroll
        for (int ni = 0; ni < 2; ++ni) {
            const int rr = wc * 32 + ni * 16 + fr;
            bofs[kk][ni] = rr * 64 + (((kk * 4 + fq) ^ (rr & 7)) * 8);
        }
    }

    f32x4 acc[4][2];
#pragma unroll
    for (int mi = 0; mi < 4; ++mi)
#pragma unroll
        for (int ni = 0; ni < 2; ++ni)
            acc[mi][ni] = (f32x4){0.f, 0.f, 0.f, 0.f};

#define COMPUTE(b)                                                             \
    do {                                                                       \
        const __hip_bfloat16* Ab = &As[(b) * 8192];                            \
        const __hip_bfloat16* Bb = &Bs[(b) * 4096];                            \
        _Pragma("unroll")                                                      \
        for (int kk = 0; kk < 2; ++kk) {                                       \
            bf16x8v af[4], bfv[2];                                             \
            _Pragma("unroll")                                                  \
            for (int mi = 0; mi < 4; ++mi)                                     \
                af[mi] = *(const bf16x8v*)&Ab[aofs[kk][mi]];                   \
            _Pragma("unroll")                                                  \
            for (int ni = 0; ni < 2; ++ni)                                     \
                bfv[ni] = *(const bf16x8v*)&Bb[bofs[kk][ni]];                  \
            _Pragma("unroll")                                                  \
            for (int mi = 0; mi < 4; ++mi)                                     \
                _Pragma("unroll")                                              \
                for (int ni = 0; ni < 2; ++ni)                                 \
                    acc[mi][ni] = __builtin_amdgcn_mfma_f32_16x16x32_bf16(     \
                        af[mi], bfv[ni], acc[mi][ni], 0, 0, 0);                \
        }                                                                      \
    } while (0)

#define WAITV(n) asm volatile("s_waitcnt vmcnt(" #n ")" ::: "memory")

    STAGE(0);                     // kt 0 -> buf0
    STAGE(1);                     // kt 1 -> buf1   (12 loads in flight)

    for (int it = 0; it < 27; ++it) {
        WAITV(6);                 // kt=2it landed
        __builtin_amdgcn_s_barrier();
        COMPUTE(0);
        __builtin_amdgcn_s_barrier();
        STAGE(0);                 // kt=2it+2 -> buf0
        WAITV(6);                 // kt=2it+1 landed
        __builtin_amdgcn_s_barrier();
        COMPUTE(1);
        __builtin_amdgcn_s_barrier();
        STAGE(1);                 // kt=2it+3 -> buf1
    }
    WAITV(6);                     // kt=54 landed
    __builtin_amdgcn_s_barrier();
    COMPUTE(0);
    WAITV(0);                     // kt=55 landed
    __builtin_amdgcn_s_barrier();
    COMPUTE(1);

#undef GLD
#undef STAGE
#undef COMPUTE
#undef WAITV

#pragma unroll
    for (int mi = 0; mi < 4; ++mi)
#pragma unroll
        for (int ni = 0; ni < 2; ++ni)
#pragma unroll
            for (int j = 0; j < 4; ++j) {
                int row = m0 + wr * 64 + mi * 16 + fq * 4 + j;
                int col = n0 + wc * 32 + ni * 16 + fr;
                float v = fminf(fmaxf(acc[mi][ni][j], 0.f), 1.f);
                a3[(size_t)row * 256 + col] = __float2bfloat16(v);
            }
}

// ---------------- MGU all steps + fc5, one kernel ----------------
__global__ __launch_bounds__(256, 1) void mgu_all_k(
    const __hip_bfloat16* __restrict__ a3,  // [10*2048][256]
    const __hip_bfloat16* __restrict__ wfi, const __hip_bfloat16* __restrict__ wfh,
    const float* __restrict__ w5, float* __restrict__ out)
{
    __shared__ __hip_bfloat16 a3_s[16 * 256];
    __shared__ __hip_bfloat16 hq_s[16 * 64];
    __shared__ float hx_s[16 * 64];
    __shared__ float w5_s[7 * 64];

    const int tid = threadIdx.x;
    const int wv  = tid >> 6, lane = tid & 63;
    const int fr  = lane & 15, fq = lane >> 4;
    const int b0  = blockIdx.x * 16;
    const int ntf = wv, ntn = wv + 4;

    bf16x8v wiF[8][2], wiN[8][2], whF[2][2], whN[2][2];
#pragma unroll
    for (int kt = 0; kt < 8; ++kt)
#pragma unroll
        for (int hl = 0; hl < 2; ++hl) {
            wiF[kt][hl] = *(const bf16x8v*)&wfi[(((ntf * 8 + kt) * 2 + hl) * 64 + lane) * 8];
            wiN[kt][hl] = *(const bf16x8v*)&wfi[(((ntn * 8 + kt) * 2 + hl) * 64 + lane) * 8];
        }
#pragma unroll
    for (int kt = 0; kt < 2; ++kt)
#pragma unroll
        for (int hl = 0; hl < 2; ++hl) {
            whF[kt][hl] = *(const bf16x8v*)&wfh[(((ntf * 2 + kt) * 2 + hl) * 64 + lane) * 8];
            whN[kt][hl] = *(const bf16x8v*)&wfh[(((ntn * 2 + kt) * 2 + hl) * 64 + lane) * 8];
        }

    for (int i = tid; i < 16 * 64; i += 256) hx_s[i] = 0.f;
    for (int i = tid; i < 7 * 64; i += 256) w5_s[i] = w5[i];
    __syncthreads();

    for (int t = 0; t < 10; ++t) {
#pragma unroll
        for (int pass = 0; pass < 2; ++pass) {
            int i = pass * 256 + tid;
            int r = i >> 5, cq = i & 31;
            bf16x8v v = *(const bf16x8v*)&a3[((size_t)(t * 2048 + b0 + r)) * 256 + cq * 8];
            *(bf16x8v*)&a3_s[r * 256 + ((cq ^ (r & 7)) * 8)] = v;
        }
#pragma unroll
        for (int pass = 0; pass < 4; ++pass) {
            int i = pass * 256 + tid;
            int r = i >> 6, c = i & 63;
            float v = hx_s[r * 64 + c];
            v = fminf(fmaxf(v, -1.f), 1.f);
            v = rintf(v * 128.f) * 0.0078125f;
            hq_s[r * 64 + (((c >> 3) ^ (r & 7)) << 3) + (c & 7)] = __float2bfloat16(v);
        }
        __syncthreads();

        f32x4 accF  = {0.f, 0.f, 0.f, 0.f};
        f32x4 accNi = {0.f, 0.f, 0.f, 0.f};
        f32x4 accNh = {0.f, 0.f, 0.f, 0.f};
#pragma unroll
        for (int kt = 0; kt < 8; ++kt) {
            bf16x8v a = *(const bf16x8v*)&a3_s[fr * 256 + (((kt * 4 + fq) ^ (fr & 7)) * 8)];
            accF  = __builtin_amdgcn_mfma_f32_16x16x32_bf16(a, wiF[kt][0], accF, 0, 0, 0);
            accF  = __builtin_amdgcn_mfma_f32_16x16x32_bf16(a, wiF[kt][1], accF, 0, 0, 0);
            accNi = __builtin_amdgcn_mfma_f32_16x16x32_bf16(a, wiN[kt][0], accNi, 0, 0, 0);
            accNi = __builtin_amdgcn_mfma_f32_16x16x32_bf16(a, wiN[kt][1], accNi, 0, 0, 0);
        }
#pragma unroll
        for (int kt = 0; kt < 2; ++kt) {
            bf16x8v a = *(const bf16x8v*)&hq_s[fr * 64 + (((kt * 4 + fq) ^ (fr & 7)) * 8)];
            accF  = __builtin_amdgcn_mfma_f32_16x16x32_bf16(a, whF[kt][0], accF, 0, 0, 0);
            accF  = __builtin_amdgcn_mfma_f32_16x16x32_bf16(a, whF[kt][1], accF, 0, 0, 0);
            accNh = __builtin_amdgcn_mfma_f32_16x16x32_bf16(a, whN[kt][0], accNh, 0, 0, 0);
            accNh = __builtin_amdgcn_mfma_f32_16x16x32_bf16(a, whN[kt][1], accNh, 0, 0, 0);
        }

        const int j5 = wv * 16 + fr;
#pragma unroll
        for (int j = 0; j < 4; ++j) {
            int b = fq * 4 + j;
            float f = fminf(fmaxf(0.5f * accF[j] + 0.5f, 0.f), 1.f);
            float n = fminf(fmaxf(accNi[j] + f * accNh[j], -1.f), 1.f);
            float hq = __bfloat162float(
                hq_s[b * 64 + ((((j5) >> 3) ^ (b & 7)) << 3) + (j5 & 7)]);
            hx_s[b * 64 + j5] = (1.f - f) * n + f * hq;
        }
        __syncthreads();
    }

    if (tid < 112) {
        int b = tid / 7, c = tid % 7;
        float acc = 0.f;
#pragma unroll
        for (int k = 0; k < 64; ++k) acc += hx_s[b * 64 + k] * w5_s[c * 64 + k];
        out[(size_t)(b0 + b) * 7 + c] = acc;
    }
}

extern "C" void kernel_launch(void* const* d_in, const int* in_sizes, int n_in,
                              void* d_out, int out_size, void* d_ws, size_t ws_size,
                              hipStream_t stream)
{
    const float* x    = (const float*)d_in[0];
    const float* w1   = (const float*)d_in[1];
    const float* w2   = (const float*)d_in[2];
    const float* fc3w = (const float*)d_in[3];
    const float* wih  = (const float*)d_in[4];
    const float* whh  = (const float*)d_in[5];
    const float* fc5w = (const float*)d_in[6];
    float* out = (float*)d_out;

    char* ws = (char*)d_ws;
    __hip_bfloat16* a2p = (__hip_bfloat16*)ws;                     // 146,800,640
    __hip_bfloat16* a3  = (__hip_bfloat16*)(ws + 146800640);       //  10,485,760
    __hip_bfloat16* w3p = (__hip_bfloat16*)(ws + 157286400);       //   1,835,008
    __hip_bfloat16* w2p = (__hip_bfloat16*)(ws + 159121408);       //      10,240
    __hip_bfloat16* wfi = (__hip_bfloat16*)(ws + 159131648);       //     131,072
    __hip_bfloat16* wfh = (__hip_bfloat16*)(ws + 159262720);       //      32,768

    cvt_all_k<<<3924, 256, 0, stream>>>(fc3w, w2, wih, whh, w3p, w2p, wfi, wfh);
    conv_all_k<<<5120, 256, 0, stream>>>(x, w1, w2p, a2p);
    fc3_all_k<<<640, 256, 0, stream>>>(a2p, w3p, a3);
    mgu_all_k<<<128, 256, 0, stream>>>(a3, wfi, wfh, fc5w, out);
}